// Round 2
// baseline (192.552 us; speedup 1.0000x reference)
//
#include <hip/hip_runtime.h>

#define ND 512   // directions
#define NP 64    // points per ray
#define NR 32    // rank
#define NF 256   // virtual subcarriers

// One block per direction d; 256 threads, thread t == frequency f.
// LDS holds att (re/im), rad (re/im), and cumsum_p(att) (re/im): 6 * 64*32*4B = 48 KB.
// Each thread keeps its fv row (32 complex) in registers, accumulates
//   first  = sum_p (conj(rad_p).fv)(conj(att_p).fv)
//   second = sum_{p>=1} first_term_p * (cum_p(att).fv)      [delta_t applied at end]
// then atomically adds the scaled contribution into out.
//
// Output layout is runtime-selected via out_layout:
//   0: real-only, out[f] = re                  (out_size == 256; complex->float32 astype)
//   1: planar,    out[f] = re, out[NF+f] = im  (out_size == 512)
__global__ __launch_bounds__(256, 2) void lowrank_raytracer_kernel(
    const float* __restrict__ att_re, const float* __restrict__ att_im,
    const float* __restrict__ rad_re, const float* __restrict__ rad_im,
    const float* __restrict__ freq_re, const float* __restrict__ freq_im,
    const int* __restrict__ mrl, float* __restrict__ out, int out_layout)
{
    __shared__ float s_ar[NP * NR], s_ai[NP * NR];
    __shared__ float s_rr[NP * NR], s_ri[NP * NR];
    __shared__ float s_cr[NP * NR], s_ci[NP * NR];

    const int t = threadIdx.x;
    const int d = blockIdx.x;
    const size_t base = (size_t)d * NP * NR;

    // Stage att/rad tile for this direction (coalesced).
    for (int i = t; i < NP * NR; i += 256) {
        s_ar[i] = att_re[base + i];
        s_ai[i] = att_im[base + i];
        s_rr[i] = rad_re[base + i];
        s_ri[i] = rad_im[base + i];
    }
    __syncthreads();

    // Prefix sum of (non-conjugated) att along p, per rank column.
    // 64 threads: t<32 does re column r=t; t in [32,64) does im column r=t-32.
    if (t < 2 * NR) {
        const int r = t & (NR - 1);
        float acc = 0.f;
        if (t < NR) {
            for (int p = 0; p < NP; ++p) { acc += s_ar[p * NR + r]; s_cr[p * NR + r] = acc; }
        } else {
            for (int p = 0; p < NP; ++p) { acc += s_ai[p * NR + r]; s_ci[p * NR + r] = acc; }
        }
    }
    __syncthreads();

    const int f = t;  // NF == blockDim.x == 256
    float fr[NR], fi[NR];
#pragma unroll
    for (int r = 0; r < NR; ++r) {
        fr[r] = freq_re[f * NR + r];
        fi[r] = freq_im[f * NR + r];
    }

    float first_re = 0.f, first_im = 0.f, sec_re = 0.f, sec_im = 0.f;

    for (int p = 0; p < NP; ++p) {
        float a_re = 0.f, a_im = 0.f;     // conj(att_p) . fv
        float b_re = 0.f, b_im = 0.f;     // conj(rad_p) . fv
        float u_re = 0.f, u_im = 0.f;     // cum_p(att) . fv   (no conj)
        const int pb = p * NR;
#pragma unroll
        for (int r = 0; r < NR; ++r) {
            const float ar = s_ar[pb + r], ai = s_ai[pb + r];
            const float rr = s_rr[pb + r], ri = s_ri[pb + r];
            const float cr = s_cr[pb + r], ci = s_ci[pb + r];
            const float vr = fr[r], vi = fi[r];
            a_re = fmaf(ar, vr, a_re); a_re = fmaf(ai, vi, a_re);
            a_im = fmaf(ar, vi, a_im); a_im = fmaf(-ai, vr, a_im);
            b_re = fmaf(rr, vr, b_re); b_re = fmaf(ri, vi, b_re);
            b_im = fmaf(rr, vi, b_im); b_im = fmaf(-ri, vr, b_im);
            u_re = fmaf(cr, vr, u_re); u_re = fmaf(-ci, vi, u_re);
            u_im = fmaf(cr, vi, u_im); u_im = fmaf(ci, vr, u_im);
        }
        // q = (conj(rad).fv) * (conj(att).fv)
        const float q_re = b_re * a_re - b_im * a_im;
        const float q_im = b_re * a_im + b_im * a_re;
        first_re += q_re;
        first_im += q_im;
        if (p >= 1) {
            sec_re += q_re * u_re - q_im * u_im;
            sec_im += q_re * u_im + q_im * u_re;
        }
    }

    const float delta_t = (float)(*mrl) / (float)NP;
    const float scale = delta_t / (float)ND;
    const float o_re = (first_re + delta_t * sec_re) * scale;
    const float o_im = (first_im + delta_t * sec_im) * scale;

    if (out_layout == 0) {
        // real-only (out_size == 256)
        atomicAdd(&out[f], o_re);
    } else {
        // planar re/im (out_size == 512)
        atomicAdd(&out[f], o_re);
        atomicAdd(&out[NF + f], o_im);
    }
}

extern "C" void kernel_launch(void* const* d_in, const int* in_sizes, int n_in,
                              void* d_out, int out_size, void* d_ws, size_t ws_size,
                              hipStream_t stream) {
    const float* att_re = (const float*)d_in[0];
    const float* att_im = (const float*)d_in[1];
    const float* rad_re = (const float*)d_in[2];
    const float* rad_im = (const float*)d_in[3];
    const float* freq_re = (const float*)d_in[4];
    const float* freq_im = (const float*)d_in[5];
    const int* mrl = (const int*)d_in[6];
    float* out = (float*)d_out;

    const int out_layout = (out_size >= 2 * NF) ? 1 : 0;

    // Harness poisons d_out with 0xAA before every timed launch; we accumulate
    // with atomics, so zero it first (memset node is graph-capture safe).
    hipMemsetAsync(d_out, 0, (size_t)out_size * sizeof(float), stream);

    lowrank_raytracer_kernel<<<ND, 256, 0, stream>>>(
        att_re, att_im, rad_re, rad_im, freq_re, freq_im, mrl, out, out_layout);
}

// Round 3
// 123.992 us; speedup vs baseline: 1.5529x; 1.5529x over previous
//
#include <hip/hip_runtime.h>

#define ND 512   // directions
#define NP 64    // points per ray
#define NR 32    // rank
#define NF 256   // virtual subcarriers

typedef __attribute__((ext_vector_type(8))) short bf16x8;   // 8 bf16 = 4 VGPRs
typedef __attribute__((ext_vector_type(4))) float f32x4;

// float -> bf16 (RNE), manual to avoid header/type issues; inputs are finite.
__device__ inline unsigned short f2bf(float x) {
    unsigned u = __builtin_bit_cast(unsigned, x);
    u += 0x7FFFu + ((u >> 16) & 1u);
    return (unsigned short)(u >> 16);
}

// One block per direction d. M = 128 rows (row 2p = "re-combo", row 2p+1 =
// "im-combo" of point p), K = 64 (re|im of rank dim), N = 256 (frequencies).
//   att/rad (conj proj):  row_re = [ xr | xi ],  row_im = [ -xi | xr ]
//   cum     (non-conj):   row_re = [ cr | -ci ], row_im = [ ci  | cr ]
//   B col f = [ freq_re[f] | freq_im[f] ]
// C[2p][f] = Re(proj), C[2p+1][f] = Im(proj); both land in the SAME lane
// (reg pairs) of the 16x16x32 C-fragment -> in-lane complex elementwise.
__global__ __launch_bounds__(256, 2) void lrrt_mfma_kernel(
    const float* __restrict__ att_re, const float* __restrict__ att_im,
    const float* __restrict__ rad_re, const float* __restrict__ rad_im,
    const float* __restrict__ freq_re, const float* __restrict__ freq_im,
    const int* __restrict__ mrl, float* __restrict__ out)
{
    __shared__ float s_c[2][NP * NR];                 // cumsum re/im: 16 KB
    __shared__ unsigned short s_afrag[3 * 8 * 2 * 64 * 8];  // A frags: 48 KB

    const int t = threadIdx.x;
    const int d = blockIdx.x;
    const size_t base = (size_t)d * (NP * NR);
    const int lane = t & 63;
    const int wv = t >> 6;          // wave 0..3, owns n-tiles 4wv..4wv+3
    const int kg = lane >> 4;       // k-group / row-group

    // --- 1. prefix sum of (non-conjugated) att along p, into LDS ---
    if (t < 64) {
        const int r = t & 31;
        const float* src = (t < 32) ? att_re : att_im;
        float* dst = s_c[t >> 5];
        float acc = 0.f;
#pragma unroll 8
        for (int p = 0; p < NP; ++p) {
            acc += src[base + p * NR + r];
            dst[p * NR + r] = acc;
        }
    }

    // --- 2. B fragments straight into registers (no LDS) ---
    // frag(q, ks): lane holds B[k = 32ks + 8kg + j][n = 16(4wv+q) + (lane&15)]
    bf16x8 bfrag[4][2];
    {
        const int n_lo = lane & 15;
#pragma unroll
        for (int q = 0; q < 4; ++q) {
            const int n = 16 * (4 * wv + q) + n_lo;
            const float4* fre = (const float4*)(freq_re + (size_t)n * NR + 8 * kg);
            const float4* fim = (const float4*)(freq_im + (size_t)n * NR + 8 * kg);
            float4 r0 = fre[0], r1 = fre[1];
            float4 i0 = fim[0], i1 = fim[1];
            bf16x8 b0, b1;
            b0[0] = f2bf(r0.x); b0[1] = f2bf(r0.y); b0[2] = f2bf(r0.z); b0[3] = f2bf(r0.w);
            b0[4] = f2bf(r1.x); b0[5] = f2bf(r1.y); b0[6] = f2bf(r1.z); b0[7] = f2bf(r1.w);
            b1[0] = f2bf(i0.x); b1[1] = f2bf(i0.y); b1[2] = f2bf(i0.z); b1[3] = f2bf(i0.w);
            b1[4] = f2bf(i1.x); b1[5] = f2bf(i1.y); b1[6] = f2bf(i1.z); b1[7] = f2bf(i1.w);
            bfrag[q][0] = b0;
            bfrag[q][1] = b1;
        }
    }

    __syncthreads();  // cumsum visible

    // --- 3. pack A fragments (bf16) into LDS in fragment order ---
    // idx = ((((proj*8 + mt)*2 + ks)*64 + L)*8 + j)
    for (int idx = t; idx < 3 * 8 * 2 * 64 * 8; idx += 256) {
        const int j = idx & 7;
        const int L = (idx >> 3) & 63;
        const int ks = (idx >> 9) & 1;
        const int mt = (idx >> 10) & 7;
        const int proj = idx >> 13;
        const int m = 16 * mt + (L & 15);
        const int p = m >> 1;
        const int s = m & 1;                  // 0 = re-row, 1 = im-row
        const int r = 8 * (L >> 4) + j;
        const size_t g = base + (size_t)p * NR + r;
        float v;
        if (proj == 0) {
            v = (s == 0) ? (ks == 0 ? att_re[g] : att_im[g])
                         : (ks == 0 ? -att_im[g] : att_re[g]);
        } else if (proj == 1) {
            v = (s == 0) ? (ks == 0 ? rad_re[g] : rad_im[g])
                         : (ks == 0 ? -rad_im[g] : rad_re[g]);
        } else {
            const float cr = s_c[0][p * NR + r];
            const float ci = s_c[1][p * NR + r];
            v = (s == 0) ? (ks == 0 ? cr : -ci)
                         : (ks == 0 ? ci : cr);
        }
        s_afrag[idx] = f2bf(v);
    }
    __syncthreads();  // A frags visible

    // --- 4. MFMA main loop ---
    const float delta_t = (float)(*mrl) / (float)NP;
    float pre[4] = {0.f, 0.f, 0.f, 0.f};
    float pim[4] = {0.f, 0.f, 0.f, 0.f};

    for (int mt = 0; mt < 8; ++mt) {
        bf16x8 afr[3][2];
#pragma unroll
        for (int proj = 0; proj < 3; ++proj)
#pragma unroll
            for (int ks = 0; ks < 2; ++ks) {
                const int off = ((((proj * 8 + mt) * 2 + ks) * 64) + lane) * 8;
                afr[proj][ks] = *(const bf16x8*)(&s_afrag[off]);
            }
#pragma unroll
        for (int q = 0; q < 4; ++q) {
            f32x4 accA = {0.f, 0.f, 0.f, 0.f};
            f32x4 accB = {0.f, 0.f, 0.f, 0.f};
            f32x4 accU = {0.f, 0.f, 0.f, 0.f};
            accA = __builtin_amdgcn_mfma_f32_16x16x32_bf16(afr[0][0], bfrag[q][0], accA, 0, 0, 0);
            accB = __builtin_amdgcn_mfma_f32_16x16x32_bf16(afr[1][0], bfrag[q][0], accB, 0, 0, 0);
            accU = __builtin_amdgcn_mfma_f32_16x16x32_bf16(afr[2][0], bfrag[q][0], accU, 0, 0, 0);
            accA = __builtin_amdgcn_mfma_f32_16x16x32_bf16(afr[0][1], bfrag[q][1], accA, 0, 0, 0);
            accB = __builtin_amdgcn_mfma_f32_16x16x32_bf16(afr[1][1], bfrag[q][1], accB, 0, 0, 0);
            accU = __builtin_amdgcn_mfma_f32_16x16x32_bf16(afr[2][1], bfrag[q][1], accU, 0, 0, 0);
#pragma unroll
            for (int rp = 0; rp < 2; ++rp) {
                const float are = accA[2 * rp], aim = accA[2 * rp + 1];
                const float bre = accB[2 * rp], bim = accB[2 * rp + 1];
                const float ure = accU[2 * rp], uim = accU[2 * rp + 1];
                const float qre = bre * are - bim * aim;
                const float qim = bre * aim + bim * are;
                const int p = 8 * mt + 2 * kg + rp;
                const float w = (p >= 1) ? delta_t : 0.f;   // p=0 excluded from 2nd term
                pre[q] += qre + w * (qre * ure - qim * uim);
                pim[q] += qim + w * (qre * uim + qim * ure);
            }
        }
    }

    // --- 5. reduce across row-groups (lanes ^16, ^32) and emit ---
    const float scale = delta_t / (float)ND;
#pragma unroll
    for (int q = 0; q < 4; ++q) {
        float re = pre[q], im = pim[q];
        re += __shfl_xor(re, 16, 64); im += __shfl_xor(im, 16, 64);
        re += __shfl_xor(re, 32, 64); im += __shfl_xor(im, 32, 64);
        if (lane < 16) {
            const int f = 16 * (4 * wv + q) + lane;
            atomicAdd(&out[f], re * scale);          // planar: re block
            atomicAdd(&out[NF + f], im * scale);     // then im block
        }
    }
}

extern "C" void kernel_launch(void* const* d_in, const int* in_sizes, int n_in,
                              void* d_out, int out_size, void* d_ws, size_t ws_size,
                              hipStream_t stream) {
    const float* att_re = (const float*)d_in[0];
    const float* att_im = (const float*)d_in[1];
    const float* rad_re = (const float*)d_in[2];
    const float* rad_im = (const float*)d_in[3];
    const float* freq_re = (const float*)d_in[4];
    const float* freq_im = (const float*)d_in[5];
    const int* mrl = (const int*)d_in[6];
    float* out = (float*)d_out;

    // d_out is poisoned 0xAA before every launch; we accumulate with atomics.
    hipMemsetAsync(d_out, 0, (size_t)out_size * sizeof(float), stream);

    lrrt_mfma_kernel<<<ND, 256, 0, stream>>>(
        att_re, att_im, rad_re, rad_im, freq_re, freq_im, mrl, out);
}